// Round 3
// 404.461 us; speedup vs baseline: 1.0487x; 1.0487x over previous
//
#include <hip/hip_runtime.h>
#include <math.h>

#define Bn 4
#define Tn 4096
#define Dn 1024
#define Nn 64
#define Rn 16
#define KCONV 4

#define TT2 32    // t-rows per prep block
#define KCH 32    // K-chunk (one 16x16x32 MFMA K-step)
#define SU 32     // scan chunk (steps per prefetch block)

typedef __attribute__((ext_vector_type(8))) short bf16x8;
typedef __attribute__((ext_vector_type(4))) float f32x4;

__device__ __forceinline__ unsigned short bf16_rne(float f) {
    unsigned int u = __float_as_uint(f);
    unsigned int r = (u + 0x7fffu + ((u >> 16) & 1u)) >> 16;
    return (unsigned short)r;
}

// Layout: intermediates live INSIDE d_out, TRANSPOSED per 64-row tile.
// For tile t0' = t & ~63 (64 consecutive t rows of one batch):
//   element (t, n) of P  -> O[(b*Tn + t0' + n)*Dn +   0 + (t - t0')]
//   element (t, n) of Dl -> O[(b*Tn + t0' + n)*Dn +  64 + (t - t0')]
//   element (t, n) of S  -> O[(b*Tn + t0' + n)*Dn + 128 + (t - t0')]
// Each scan lane (fixed n) thus reads/writes CONTIGUOUS floats over t.
// out_kernel still only touches its own 64 rows before overwriting them.

// ---------------------------------------------------------------------------
// Kernel 1 (MFMA bf16x3): fused conv + input proj + delta path.  (unchanged,
// identical to the 422us-verified version)
// ---------------------------------------------------------------------------
__global__ __launch_bounds__(128)
void prep_kernel(const float* __restrict__ x, const float* __restrict__ conv_w,
                 const float* __restrict__ in_w, const float* __restrict__ in_b,
                 const float* __restrict__ dt_w, const float* __restrict__ dt_b,
                 const float* __restrict__ tr_w,
                 float* __restrict__ O)
{
    __shared__ bf16x8 Axc_h[2][64], Axc_l[2][64];   // A = x+conv (hi/lo)
    __shared__ bf16x8 Axr_h[2][64], Axr_l[2][64];   // A = raw x  (hi/lo)
    __shared__ bf16x8 Bw_h[4][64],  Bw_l[4][64];    // B = in_w rows (hi/lo)
    __shared__ bf16x8 Bd_h[64],     Bd_l[64];       // B = dt_w rows (hi/lo)
    __shared__ float  AsS[TT2][17];                 // tanh activations
    __shared__ float  trS[Nn][17];                  // tr_w padded

    const int tid = threadIdx.x;
    const int b   = blockIdx.y;
    const int t0  = blockIdx.x * TT2;
    const int l   = tid & 63;
    const int w   = tid >> 6;

    const float* xb = x + (size_t)b * Tn * Dn;

    for (int idx = tid; idx < Nn * Rn; idx += 128)
        trS[idx >> 4][idx & 15] = tr_w[idx];

    const f32x4 z4 = {0.f, 0.f, 0.f, 0.f};
    f32x4 accP[4] = {z4, z4, z4, z4};
    f32x4 accG = z4;

    for (int kc = 0; kc < Dn / KCH; ++kc) {
        const int k0 = kc * KCH;
        __syncthreads();

        // ---- stage A fragments: conv + hi/lo split
        {
            const int m  = tid & 31;
            const int s  = tid >> 5;
            const int t  = t0 + m;
            const int gk = k0 + 8 * s;
            float v[4][8];
            #pragma unroll
            for (int dr = 0; dr < 4; ++dr) {
                int tp = t - 3 + dr;
                if (tp >= 0) {
                    float4 a  = *(const float4*)&xb[(size_t)tp * Dn + gk];
                    float4 bq = *(const float4*)&xb[(size_t)tp * Dn + gk + 4];
                    v[dr][0]=a.x;  v[dr][1]=a.y;  v[dr][2]=a.z;  v[dr][3]=a.w;
                    v[dr][4]=bq.x; v[dr][5]=bq.y; v[dr][6]=bq.z; v[dr][7]=bq.w;
                } else {
                    #pragma unroll
                    for (int k = 0; k < 8; ++k) v[dr][k] = 0.f;
                }
            }
            bf16x8 fch, fcl, frh, frl;
            #pragma unroll
            for (int k = 0; k < 8; ++k) {
                float4 cw = *(const float4*)&conv_w[(size_t)(gk + k) * 4];
                float xr = v[3][k];
                float xc = xr;
                xc = fmaf(v[0][k], cw.x, xc);
                xc = fmaf(v[1][k], cw.y, xc);
                xc = fmaf(v[2][k], cw.z, xc);
                xc = fmaf(v[3][k], cw.w, xc);
                unsigned short h; float hf;
                h = bf16_rne(xc); hf = __uint_as_float((unsigned)h << 16);
                fch[k] = (short)h; fcl[k] = (short)bf16_rne(xc - hf);
                h = bf16_rne(xr); hf = __uint_as_float((unsigned)h << 16);
                frh[k] = (short)h; frl[k] = (short)bf16_rne(xr - hf);
            }
            const int lane = (m & 15) | (s << 4), mt = m >> 4;
            Axc_h[mt][lane] = fch; Axc_l[mt][lane] = fcl;
            Axr_h[mt][lane] = frh; Axr_l[mt][lane] = frl;
        }
        // ---- stage B fragments
        #pragma unroll
        for (int rep = 0; rep < 2; ++rep) {
            int slot = tid + rep * 128;
            int n = slot & 63, s = slot >> 6;
            const float* wp = &in_w[(size_t)n * Dn + k0 + 8 * s];
            float4 a  = *(const float4*)wp;
            float4 bq = *(const float4*)(wp + 4);
            float wv[8] = {a.x, a.y, a.z, a.w, bq.x, bq.y, bq.z, bq.w};
            bf16x8 fh, fl;
            #pragma unroll
            for (int k = 0; k < 8; ++k) {
                unsigned short h = bf16_rne(wv[k]);
                float hf = __uint_as_float((unsigned)h << 16);
                fh[k] = (short)h; fl[k] = (short)bf16_rne(wv[k] - hf);
            }
            Bw_h[n >> 4][(n & 15) | (s << 4)] = fh;
            Bw_l[n >> 4][(n & 15) | (s << 4)] = fl;
        }
        if (tid < 64) {
            int r = tid & 15, s = tid >> 4;
            const float* wp = &dt_w[(size_t)r * Dn + k0 + 8 * s];
            float4 a  = *(const float4*)wp;
            float4 bq = *(const float4*)(wp + 4);
            float wv[8] = {a.x, a.y, a.z, a.w, bq.x, bq.y, bq.z, bq.w};
            bf16x8 fh, fl;
            #pragma unroll
            for (int k = 0; k < 8; ++k) {
                unsigned short h = bf16_rne(wv[k]);
                float hf = __uint_as_float((unsigned)h << 16);
                fh[k] = (short)h; fl[k] = (short)bf16_rne(wv[k] - hf);
            }
            Bd_h[tid] = fh; Bd_l[tid] = fl;
        }
        __syncthreads();

        // ---- MFMA phase: bf16x3 = Ah*Bh + Al*Bh + Ah*Bl
        bf16x8 axh = Axc_h[w][l], axl = Axc_l[w][l];
        bf16x8 arh = Axr_h[w][l], arl = Axr_l[w][l];
        #pragma unroll
        for (int nt = 0; nt < 4; ++nt) {
            bf16x8 bh = Bw_h[nt][l], bl = Bw_l[nt][l];
            accP[nt] = __builtin_amdgcn_mfma_f32_16x16x32_bf16(axh, bh, accP[nt], 0, 0, 0);
            accP[nt] = __builtin_amdgcn_mfma_f32_16x16x32_bf16(axl, bh, accP[nt], 0, 0, 0);
            accP[nt] = __builtin_amdgcn_mfma_f32_16x16x32_bf16(axh, bl, accP[nt], 0, 0, 0);
        }
        {
            bf16x8 bh = Bd_h[l], bl = Bd_l[l];
            accG = __builtin_amdgcn_mfma_f32_16x16x32_bf16(arh, bh, accG, 0, 0, 0);
            accG = __builtin_amdgcn_mfma_f32_16x16x32_bf16(arl, bh, accG, 0, 0, 0);
            accG = __builtin_amdgcn_mfma_f32_16x16x32_bf16(arh, bl, accG, 0, 0, 0);
        }
    }

    // ---- epilogue: As = tanh(G + dt_b); Dl = As @ tr_w.T; write P, Dl
    __syncthreads();
    #pragma unroll
    for (int i = 0; i < 4; ++i)
        AsS[16 * w + 4 * (l >> 4) + i][l & 15] = tanhf(accG[i] + dt_b[l & 15]);
    __syncthreads();

    float as_[4][16];
    #pragma unroll
    for (int i = 0; i < 4; ++i) {
        int mrow = 16 * w + 4 * (l >> 4) + i;
        #pragma unroll
        for (int j = 0; j < 4; ++j) {
            float4 q = *(const float4*)&AsS[mrow][4 * j];
            as_[i][4*j] = q.x; as_[i][4*j+1] = q.y;
            as_[i][4*j+2] = q.z; as_[i][4*j+3] = q.w;
        }
    }
    const int tile0 = t0 & ~63;        // 64-aligned tile base (t0 is 0 or 32 mod 64)
    const int coff  = t0 & 63;         // col offset of this block's 32 rows
    #pragma unroll
    for (int nt = 0; nt < 4; ++nt) {
        int n = 16 * nt + (l & 15);
        float tw[16];
        #pragma unroll
        for (int j = 0; j < 4; ++j) {
            float4 q = *(const float4*)&trS[n][4 * j];
            tw[4*j] = q.x; tw[4*j+1] = q.y; tw[4*j+2] = q.z; tw[4*j+3] = q.w;
        }
        float ib = in_b[n];
        #pragma unroll
        for (int i = 0; i < 4; ++i) {
            int mrow = 16 * w + 4 * (l >> 4) + i;
            float dlv = 0.f;
            #pragma unroll
            for (int r = 0; r < 16; ++r) dlv = fmaf(as_[i][r], tw[r], dlv);
            // transposed write: row = tile0 + n, col = coff + mrow
            size_t a = ((size_t)(b * Tn + tile0 + n)) * Dn + coff + mrow;
            O[a]      = accP[nt][i] + ib;
            O[a + 64] = dlv;
        }
    }
}

// ---------------------------------------------------------------------------
// Kernel 2: sequential scan, LDS-staged prefetch. grid (B), block 64 (1 wave).
// Lane n owns chain n.
//
// Why LDS staging: the two failed register-prefetch variants had the classic
// async-asm hazard — loads write PHYSICAL registers asynchronously, and any
// allocator live-range split (loop-carried tuples) makes data land in a dead
// phys reg. global_load_lds has no register destination, so no such hazard.
//
// vmcnt ledger (robust-by-construction):
//   iter c: issue 16 global_load_lds for chunk c+1  -> newest 16 ops
//           s_waitcnt vmcnt(16)                      -> keep ONLY those 16;
//             drains chunk c's loads (issued ~900cy ago, free) and ALL stores
//             (issued at top of previous compute, ~900cy old, free).
//           store S_{c-1} from regs (8 stores, top of compute -> they age a
//             full chunk before the next wait)
//           compute chunk c from LDS (compiler-managed lgkmcnt), S_c -> regs
//   Store COUNT never appears in a keep-set => immune to codegen surprises.
//   Epilogue: vmcnt(0) once (everything old), compute last chunk.
// ---------------------------------------------------------------------------

typedef const __attribute__((address_space(1))) void GVoid;
typedef __attribute__((address_space(3))) void LVoid;

#define WAITV(N) do {                                                    \
    asm volatile("s_waitcnt vmcnt(" #N ")" ::: "memory");                \
    __builtin_amdgcn_sched_barrier(0);                                   \
} while (0)

// Issue one chunk: 16 x (64 lanes x 16B). LDS dst is uniform; HW adds lane*16.
// LDS layout per buffer: [16 segs][64 lanes][4 floats]; segs 0-7 = P, 8-15 = Dl.
__device__ __forceinline__ void issue_chunk(float* lds, const float* rp)
{
    #pragma unroll
    for (int j = 0; j < 8; ++j)
        __builtin_amdgcn_global_load_lds((GVoid*)(rp + 4 * j),
                                         (LVoid*)(lds + j * 256), 16, 0, 0);
    #pragma unroll
    for (int j = 0; j < 8; ++j)
        __builtin_amdgcn_global_load_lds((GVoid*)(rp + 64 + 4 * j),
                                         (LVoid*)(lds + (8 + j) * 256), 16, 0, 0);
}

// Store prev chunk's S (if sp), then compute 32 steps from LDS into sv/st.
__device__ __forceinline__ void scan_chunk(const float* buf, int n, float& st,
                                           f32x4 (&sv)[8], float* sp)
{
    const float L2E = 1.44269504088896340736f;
    if (sp) {
        #pragma unroll
        for (int j = 0; j < 8; ++j)
            *(f32x4*)(sp + 4 * j) = sv[j];
    }
    #pragma unroll
    for (int j = 0; j < 8; ++j) {
        f32x4 pv = *(const f32x4*)(buf + j * 256 + n * 4);
        f32x4 dv = *(const f32x4*)(buf + (8 + j) * 256 + n * 4);
        #pragma unroll
        for (int i = 0; i < 4; ++i) {
            float d  = dv[i];
            float u  = st + d;                                  // off critical path
            float e  = __builtin_amdgcn_exp2f(fmaf(st, -L2E, -d * L2E));
            float r  = __builtin_amdgcn_rcpf(1.f + e);
            st = fmaf(u, r, pv[i]);
            sv[j][i] = st;
        }
    }
}

__global__ __launch_bounds__(64, 1)
void scan_kernel(float* __restrict__ O)
{
    __shared__ __align__(16) float bufA[16 * 64 * 4];   // even chunks
    __shared__ __align__(16) float bufB[16 * 64 * 4];   // odd chunks

    const int b = blockIdx.x;
    const int n = threadIdx.x;
    float* obase = O + (size_t)b * Tn * Dn;

    // chunk c source base (per lane): obase + ((c>>1)*64 + n)*Dn + (c&1)*32
    // S of chunk c: same + 128.

    f32x4 sv[8];
    float st = 0.f;

    // ---- prologue: chunks 0,1 in flight; compute chunk 0 (no store yet)
    const float* rp0 = obase + (size_t)n * Dn;
    issue_chunk(bufA, rp0);            // L0
    issue_chunk(bufB, rp0 + 32);       // L1
    WAITV(16);                         // drain L0, keep L1
    scan_chunk(bufA, n, st, sv, nullptr);   // chunk 0 -> sv = S_0

    // ---- steady state: c = 1..126
    #pragma unroll 1
    for (int c = 1; c < Tn / SU - 1; ++c) {
        const int cn = c + 1;
        const float* rpn = obase + (size_t)((cn >> 1) * 64 + n) * Dn + (cn & 1) * 32;
        issue_chunk((cn & 1) ? bufB : bufA, rpn);   // L_{c+1}
        WAITV(16);                                  // keep L_{c+1} only
        float* sp = obase + (size_t)(((c - 1) >> 1) * 64 + n) * Dn
                  + ((c - 1) & 1) * 32 + 128;       // S_{c-1} dest
        scan_chunk((c & 1) ? bufB : bufA, n, st, sv, sp);  // chunk c -> sv = S_c
    }

    // ---- epilogue: chunk 127 (odd -> bufB); then store S_127
    WAITV(0);
    {
        const int c = Tn / SU - 1;                  // 127
        float* sp = obase + (size_t)(((c - 1) >> 1) * 64 + n) * Dn
                  + ((c - 1) & 1) * 32 + 128;       // S_126 dest
        scan_chunk(bufB, n, st, sv, sp);
        float* spL = obase + (size_t)((c >> 1) * 64 + n) * Dn + (c & 1) * 32 + 128;
        #pragma unroll
        for (int j = 0; j < 8; ++j)
            *(f32x4*)(spL + 4 * j) = sv[j];
    }
}

// ---------------------------------------------------------------------------
// Kernel 3: output projection, in-place. grid (BT/64), block 256. (unchanged)
// ---------------------------------------------------------------------------
__global__ __launch_bounds__(256)
void out_kernel(const float* __restrict__ out_w, const float* __restrict__ out_b,
                float* __restrict__ O)
{
    __shared__ float Ss[64][Nn + 4];   // Ss[t_local][n]
    __shared__ float wT[Nn][64 + 4];

    const int tid = threadIdx.x;
    const int r0  = blockIdx.x * 64;
    const int c   = tid & 15;
    const int g   = tid >> 4;

    // stage S: element (t = r0+tl, n) lives at O[(r0+n)*Dn + 128 + tl]
    for (int idx = tid; idx < 64 * 16; idx += 256) {
        int nn = idx >> 4, tg = idx & 15;
        float4 v = *(const float4*)&O[(size_t)(r0 + nn) * Dn + 128 + 4 * tg];
        Ss[4 * tg + 0][nn] = v.x;
        Ss[4 * tg + 1][nn] = v.y;
        Ss[4 * tg + 2][nn] = v.z;
        Ss[4 * tg + 3][nn] = v.w;
    }
    __syncthreads();

    for (int cb = 0; cb < Dn / 64; ++cb) {
        const int d0 = cb * 64;
        for (int idx = tid; idx < Nn * 64 / 4; idx += 256) {
            int dl = idx >> 4, n4 = (idx & 15) * 4;
            float4 wv = *(const float4*)&out_w[(size_t)(d0 + dl) * Nn + n4];
            wT[n4 + 0][dl] = wv.x;
            wT[n4 + 1][dl] = wv.y;
            wT[n4 + 2][dl] = wv.z;
            wT[n4 + 3][dl] = wv.w;
        }
        __syncthreads();

        float acc[4][4] = {};
        #pragma unroll
        for (int kq = 0; kq < Nn; kq += 4) {
            float4 wv0 = *(const float4*)&wT[kq + 0][4 * c];
            float4 wv1 = *(const float4*)&wT[kq + 1][4 * c];
            float4 wv2 = *(const float4*)&wT[kq + 2][4 * c];
            float4 wv3 = *(const float4*)&wT[kq + 3][4 * c];
            #pragma unroll
            for (int i = 0; i < 4; ++i) {
                int row = g + 16 * i;
                float4 xv = *(const float4*)&Ss[row][kq];
                acc[i][0] = fmaf(xv.x, wv0.x, fmaf(xv.y, wv1.x, fmaf(xv.z, wv2.x, fmaf(xv.w, wv3.x, acc[i][0]))));
                acc[i][1] = fmaf(xv.x, wv0.y, fmaf(xv.y, wv1.y, fmaf(xv.z, wv2.y, fmaf(xv.w, wv3.y, acc[i][1]))));
                acc[i][2] = fmaf(xv.x, wv0.z, fmaf(xv.y, wv1.z, fmaf(xv.z, wv2.z, fmaf(xv.w, wv3.z, acc[i][2]))));
                acc[i][3] = fmaf(xv.x, wv0.w, fmaf(xv.y, wv1.w, fmaf(xv.z, wv2.w, fmaf(xv.w, wv3.w, acc[i][3]))));
            }
        }

        float4 bb = *(const float4*)&out_b[d0 + 4 * c];
        #pragma unroll
        for (int i = 0; i < 4; ++i) {
            int row = g + 16 * i;
            float4 o = make_float4(acc[i][0] + bb.x, acc[i][1] + bb.y,
                                   acc[i][2] + bb.z, acc[i][3] + bb.w);
            *(float4*)&O[(size_t)(r0 + row) * Dn + d0 + 4 * c] = o;
        }
        __syncthreads();
    }
}

extern "C" void kernel_launch(void* const* d_in, const int* in_sizes, int n_in,
                              void* d_out, int out_size, void* d_ws, size_t ws_size,
                              hipStream_t stream)
{
    const float* x      = (const float*)d_in[0];
    const float* conv_w = (const float*)d_in[1];
    const float* in_w   = (const float*)d_in[2];
    const float* in_b   = (const float*)d_in[3];
    const float* dt_w   = (const float*)d_in[4];
    const float* dt_b   = (const float*)d_in[5];
    const float* tr_w   = (const float*)d_in[6];
    const float* out_w  = (const float*)d_in[7];
    const float* out_b  = (const float*)d_in[8];
    float* O = (float*)d_out;
    (void)d_ws; (void)ws_size;

    dim3 g1(Tn / TT2, Bn);
    prep_kernel<<<g1, 128, 0, stream>>>(x, conv_w, in_w, in_b, dt_w, dt_b, tr_w, O);

    scan_kernel<<<dim3(Bn), 64, 0, stream>>>(O);

    out_kernel<<<dim3((Bn * Tn) / 64), 256, 0, stream>>>(out_w, out_b, O);
}

// Round 4
// 384.230 us; speedup vs baseline: 1.1039x; 1.0527x over previous
//
#include <hip/hip_runtime.h>
#include <math.h>

#define Bn 4
#define Tn 4096
#define Dn 1024
#define Nn 64
#define Rn 16
#define KCONV 4

#define TT2 32    // t-rows per prep block
#define KCH 32    // K-chunk (one 16x16x32 MFMA K-step)
#define SU 32     // scan chunk (steps per prefetch block)

typedef __attribute__((ext_vector_type(8))) short bf16x8;
typedef __attribute__((ext_vector_type(4))) float f32x4;

__device__ __forceinline__ unsigned short bf16_rne(float f) {
    unsigned int u = __float_as_uint(f);
    unsigned int r = (u + 0x7fffu + ((u >> 16) & 1u)) >> 16;
    return (unsigned short)r;
}

// Layout: intermediates live INSIDE d_out, TRANSPOSED per 64-row tile.
// For tile t0' = t & ~63 (64 consecutive t rows of one batch):
//   element (t, n) of P  -> O[(b*Tn + t0' + n)*Dn +   0 + (t - t0')]
//   element (t, n) of Dl -> O[(b*Tn + t0' + n)*Dn +  64 + (t - t0')]
//   element (t, n) of S  -> O[(b*Tn + t0' + n)*Dn + 128 + (t - t0')]
// Each scan lane (fixed n) thus reads/writes CONTIGUOUS floats over t.
// out_kernel still only touches its own 64 rows before overwriting them.

// ---------------------------------------------------------------------------
// Kernel 1 (MFMA bf16x3): fused conv + input proj + delta path.  (unchanged,
// identical to the 404us-verified version)
// ---------------------------------------------------------------------------
__global__ __launch_bounds__(128)
void prep_kernel(const float* __restrict__ x, const float* __restrict__ conv_w,
                 const float* __restrict__ in_w, const float* __restrict__ in_b,
                 const float* __restrict__ dt_w, const float* __restrict__ dt_b,
                 const float* __restrict__ tr_w,
                 float* __restrict__ O)
{
    __shared__ bf16x8 Axc_h[2][64], Axc_l[2][64];   // A = x+conv (hi/lo)
    __shared__ bf16x8 Axr_h[2][64], Axr_l[2][64];   // A = raw x  (hi/lo)
    __shared__ bf16x8 Bw_h[4][64],  Bw_l[4][64];    // B = in_w rows (hi/lo)
    __shared__ bf16x8 Bd_h[64],     Bd_l[64];       // B = dt_w rows (hi/lo)
    __shared__ float  AsS[TT2][17];                 // tanh activations
    __shared__ float  trS[Nn][17];                  // tr_w padded

    const int tid = threadIdx.x;
    const int b   = blockIdx.y;
    const int t0  = blockIdx.x * TT2;
    const int l   = tid & 63;
    const int w   = tid >> 6;

    const float* xb = x + (size_t)b * Tn * Dn;

    for (int idx = tid; idx < Nn * Rn; idx += 128)
        trS[idx >> 4][idx & 15] = tr_w[idx];

    const f32x4 z4 = {0.f, 0.f, 0.f, 0.f};
    f32x4 accP[4] = {z4, z4, z4, z4};
    f32x4 accG = z4;

    for (int kc = 0; kc < Dn / KCH; ++kc) {
        const int k0 = kc * KCH;
        __syncthreads();

        // ---- stage A fragments: conv + hi/lo split
        {
            const int m  = tid & 31;
            const int s  = tid >> 5;
            const int t  = t0 + m;
            const int gk = k0 + 8 * s;
            float v[4][8];
            #pragma unroll
            for (int dr = 0; dr < 4; ++dr) {
                int tp = t - 3 + dr;
                if (tp >= 0) {
                    float4 a  = *(const float4*)&xb[(size_t)tp * Dn + gk];
                    float4 bq = *(const float4*)&xb[(size_t)tp * Dn + gk + 4];
                    v[dr][0]=a.x;  v[dr][1]=a.y;  v[dr][2]=a.z;  v[dr][3]=a.w;
                    v[dr][4]=bq.x; v[dr][5]=bq.y; v[dr][6]=bq.z; v[dr][7]=bq.w;
                } else {
                    #pragma unroll
                    for (int k = 0; k < 8; ++k) v[dr][k] = 0.f;
                }
            }
            bf16x8 fch, fcl, frh, frl;
            #pragma unroll
            for (int k = 0; k < 8; ++k) {
                float4 cw = *(const float4*)&conv_w[(size_t)(gk + k) * 4];
                float xr = v[3][k];
                float xc = xr;
                xc = fmaf(v[0][k], cw.x, xc);
                xc = fmaf(v[1][k], cw.y, xc);
                xc = fmaf(v[2][k], cw.z, xc);
                xc = fmaf(v[3][k], cw.w, xc);
                unsigned short h; float hf;
                h = bf16_rne(xc); hf = __uint_as_float((unsigned)h << 16);
                fch[k] = (short)h; fcl[k] = (short)bf16_rne(xc - hf);
                h = bf16_rne(xr); hf = __uint_as_float((unsigned)h << 16);
                frh[k] = (short)h; frl[k] = (short)bf16_rne(xr - hf);
            }
            const int lane = (m & 15) | (s << 4), mt = m >> 4;
            Axc_h[mt][lane] = fch; Axc_l[mt][lane] = fcl;
            Axr_h[mt][lane] = frh; Axr_l[mt][lane] = frl;
        }
        // ---- stage B fragments
        #pragma unroll
        for (int rep = 0; rep < 2; ++rep) {
            int slot = tid + rep * 128;
            int n = slot & 63, s = slot >> 6;
            const float* wp = &in_w[(size_t)n * Dn + k0 + 8 * s];
            float4 a  = *(const float4*)wp;
            float4 bq = *(const float4*)(wp + 4);
            float wv[8] = {a.x, a.y, a.z, a.w, bq.x, bq.y, bq.z, bq.w};
            bf16x8 fh, fl;
            #pragma unroll
            for (int k = 0; k < 8; ++k) {
                unsigned short h = bf16_rne(wv[k]);
                float hf = __uint_as_float((unsigned)h << 16);
                fh[k] = (short)h; fl[k] = (short)bf16_rne(wv[k] - hf);
            }
            Bw_h[n >> 4][(n & 15) | (s << 4)] = fh;
            Bw_l[n >> 4][(n & 15) | (s << 4)] = fl;
        }
        if (tid < 64) {
            int r = tid & 15, s = tid >> 4;
            const float* wp = &dt_w[(size_t)r * Dn + k0 + 8 * s];
            float4 a  = *(const float4*)wp;
            float4 bq = *(const float4*)(wp + 4);
            float wv[8] = {a.x, a.y, a.z, a.w, bq.x, bq.y, bq.z, bq.w};
            bf16x8 fh, fl;
            #pragma unroll
            for (int k = 0; k < 8; ++k) {
                unsigned short h = bf16_rne(wv[k]);
                float hf = __uint_as_float((unsigned)h << 16);
                fh[k] = (short)h; fl[k] = (short)bf16_rne(wv[k] - hf);
            }
            Bd_h[tid] = fh; Bd_l[tid] = fl;
        }
        __syncthreads();

        // ---- MFMA phase: bf16x3 = Ah*Bh + Al*Bh + Ah*Bl
        bf16x8 axh = Axc_h[w][l], axl = Axc_l[w][l];
        bf16x8 arh = Axr_h[w][l], arl = Axr_l[w][l];
        #pragma unroll
        for (int nt = 0; nt < 4; ++nt) {
            bf16x8 bh = Bw_h[nt][l], bl = Bw_l[nt][l];
            accP[nt] = __builtin_amdgcn_mfma_f32_16x16x32_bf16(axh, bh, accP[nt], 0, 0, 0);
            accP[nt] = __builtin_amdgcn_mfma_f32_16x16x32_bf16(axl, bh, accP[nt], 0, 0, 0);
            accP[nt] = __builtin_amdgcn_mfma_f32_16x16x32_bf16(axh, bl, accP[nt], 0, 0, 0);
        }
        {
            bf16x8 bh = Bd_h[l], bl = Bd_l[l];
            accG = __builtin_amdgcn_mfma_f32_16x16x32_bf16(arh, bh, accG, 0, 0, 0);
            accG = __builtin_amdgcn_mfma_f32_16x16x32_bf16(arl, bh, accG, 0, 0, 0);
            accG = __builtin_amdgcn_mfma_f32_16x16x32_bf16(arh, bl, accG, 0, 0, 0);
        }
    }

    // ---- epilogue: As = tanh(G + dt_b); Dl = As @ tr_w.T; write P, Dl
    __syncthreads();
    #pragma unroll
    for (int i = 0; i < 4; ++i)
        AsS[16 * w + 4 * (l >> 4) + i][l & 15] = tanhf(accG[i] + dt_b[l & 15]);
    __syncthreads();

    float as_[4][16];
    #pragma unroll
    for (int i = 0; i < 4; ++i) {
        int mrow = 16 * w + 4 * (l >> 4) + i;
        #pragma unroll
        for (int j = 0; j < 4; ++j) {
            float4 q = *(const float4*)&AsS[mrow][4 * j];
            as_[i][4*j] = q.x; as_[i][4*j+1] = q.y;
            as_[i][4*j+2] = q.z; as_[i][4*j+3] = q.w;
        }
    }
    const int tile0 = t0 & ~63;        // 64-aligned tile base (t0 is 0 or 32 mod 64)
    const int coff  = t0 & 63;         // col offset of this block's 32 rows
    #pragma unroll
    for (int nt = 0; nt < 4; ++nt) {
        int n = 16 * nt + (l & 15);
        float tw[16];
        #pragma unroll
        for (int j = 0; j < 4; ++j) {
            float4 q = *(const float4*)&trS[n][4 * j];
            tw[4*j] = q.x; tw[4*j+1] = q.y; tw[4*j+2] = q.z; tw[4*j+3] = q.w;
        }
        float ib = in_b[n];
        #pragma unroll
        for (int i = 0; i < 4; ++i) {
            int mrow = 16 * w + 4 * (l >> 4) + i;
            float dlv = 0.f;
            #pragma unroll
            for (int r = 0; r < 16; ++r) dlv = fmaf(as_[i][r], tw[r], dlv);
            // transposed write: row = tile0 + n, col = coff + mrow
            size_t a = ((size_t)(b * Tn + tile0 + n)) * Dn + coff + mrow;
            O[a]      = accP[nt][i] + ib;
            O[a + 64] = dlv;
        }
    }
}

// ---------------------------------------------------------------------------
// Kernel 2: sequential scan, LDS-staged, distance-2 prefetch, asm ds_read.
// grid (B), block 64 (1 wave). Lane n owns chain n.
//
// Round-3 post-mortem: 2604 cyc/chunk vs ~900 compute. Root-cause candidate:
// SIInsertWaitcnts can't prove the C++ LDS reads don't alias the just-issued
// LDS-DMA -> conservative vmcnt(0) before every chunk's reads, nullifying the
// counted vmcnt(16). Fix: reads live in ONE volatile asm block (16x
// ds_read_b128 + lgkmcnt(0) INSIDE it -> no async-register hazard, no
// compiler-visible LDS read). Distance-2 (3 buffers) gives loads ~2 compute
// phases (~1800cy) of cover.
//
// vmcnt ledger (in-order retirement; L=16 loads, S=8 stores; iteration c
// does: issue L_{c+2} -> WAITV -> store S_{c-1} -> asm-read buf_c -> compute):
//   queue at WAITV of iter c: [..., L_c, S_{c-3}, L_{c+1}, S_{c-2}, L_{c+2}]
//   entries newer than L_c = 8+16+8+16 = 48 -> N<=48 drains L_c.
//   N=40 keeps exactly [L_{c+1}, S_{c-2}, L_{c+2}].   (steady state, c>=2)
//   prologue: [L0,L1,L2] WAITV(32) keeps [L1,L2];
//   c=1: [L1,L2,L3] WAITV(32) keeps [L2,L3];
//   c=126 (no issue): [L126,S123,L127,S124] WAITV(24) keeps [S124,L127];
//   c=127: [L127,S124,S125] WAITV(16) drains L127.
// ---------------------------------------------------------------------------

typedef const __attribute__((address_space(1))) void GVoid;
typedef __attribute__((address_space(3))) void LVoid;
typedef __attribute__((address_space(3))) float LdsFloat;

#define WAITV(N) do {                                                    \
    asm volatile("s_waitcnt vmcnt(" #N ")" ::: "memory");                \
    __builtin_amdgcn_sched_barrier(0);                                   \
} while (0)

// Issue one chunk: 16 x (64 lanes x 16B). LDS dst is uniform; HW adds lane*16.
// LDS layout per buffer: [16 segs][64 lanes][4 floats]; segs 0-7 = P, 8-15 = Dl.
__device__ __forceinline__ void issue_chunk(float* lds, const float* rp)
{
    #pragma unroll
    for (int j = 0; j < 8; ++j)
        __builtin_amdgcn_global_load_lds((GVoid*)(rp + 4 * j),
                                         (LVoid*)(lds + j * 256), 16, 0, 0);
    #pragma unroll
    for (int j = 0; j < 8; ++j)
        __builtin_amdgcn_global_load_lds((GVoid*)(rp + 64 + 4 * j),
                                         (LVoid*)(lds + (8 + j) * 256), 16, 0, 0);
}

// All 16 ds_read_b128 + lgkmcnt(0) in ONE asm block: results are guaranteed
// architecturally complete at asm exit (no live-range-split hazard), and the
// compiler sees no LDS read to insert conservative vmcnt waits for.
#define DS_READ_ALL(pv, dv, a)                                           \
    asm volatile(                                                        \
        "ds_read_b128 %0, %16 offset:0\n\t"                              \
        "ds_read_b128 %1, %16 offset:1024\n\t"                           \
        "ds_read_b128 %2, %16 offset:2048\n\t"                           \
        "ds_read_b128 %3, %16 offset:3072\n\t"                           \
        "ds_read_b128 %4, %16 offset:4096\n\t"                           \
        "ds_read_b128 %5, %16 offset:5120\n\t"                           \
        "ds_read_b128 %6, %16 offset:6144\n\t"                           \
        "ds_read_b128 %7, %16 offset:7168\n\t"                           \
        "ds_read_b128 %8, %16 offset:8192\n\t"                           \
        "ds_read_b128 %9, %16 offset:9216\n\t"                           \
        "ds_read_b128 %10, %16 offset:10240\n\t"                         \
        "ds_read_b128 %11, %16 offset:11264\n\t"                         \
        "ds_read_b128 %12, %16 offset:12288\n\t"                         \
        "ds_read_b128 %13, %16 offset:13312\n\t"                         \
        "ds_read_b128 %14, %16 offset:14336\n\t"                         \
        "ds_read_b128 %15, %16 offset:15360\n\t"                         \
        "s_waitcnt lgkmcnt(0)"                                           \
        : "=&v"(pv[0]), "=&v"(pv[1]), "=&v"(pv[2]), "=&v"(pv[3]),        \
          "=&v"(pv[4]), "=&v"(pv[5]), "=&v"(pv[6]), "=&v"(pv[7]),        \
          "=&v"(dv[0]), "=&v"(dv[1]), "=&v"(dv[2]), "=&v"(dv[3]),        \
          "=&v"(dv[4]), "=&v"(dv[5]), "=&v"(dv[6]), "=&v"(dv[7])         \
        : "v"(a) : "memory")

__device__ __forceinline__ void store_s(float* sp, const f32x4 (&sv)[8])
{
    #pragma unroll
    for (int j = 0; j < 8; ++j)
        *(f32x4*)(sp + 4 * j) = sv[j];
}

__device__ __forceinline__ void compute_chunk(const float* buf, int n,
                                              float& st, f32x4 (&sv)[8])
{
    const float L2E = 1.44269504088896340736f;
    unsigned a = (unsigned)(unsigned long long)(LdsFloat*)buf
               + (unsigned)(n * 16);
    f32x4 pv[8], dv[8];
    DS_READ_ALL(pv, dv, a);
    __builtin_amdgcn_sched_barrier(0);
    #pragma unroll
    for (int j = 0; j < 8; ++j) {
        #pragma unroll
        for (int i = 0; i < 4; ++i) {
            float d  = dv[j][i];
            float u  = st + d;                                  // off critical path
            float e  = __builtin_amdgcn_exp2f(fmaf(st, -L2E, -d * L2E));
            float r  = __builtin_amdgcn_rcpf(1.f + e);
            st = fmaf(u, r, pv[j][i]);
            sv[j][i] = st;
        }
    }
}

// chunk c (c = 0..127): global base for lane n
#define RP(c) (obase + (size_t)((((c) >> 1) * 64) + n) * Dn + ((c) & 1) * 32)
#define SP(c) (RP(c) + 128)

__global__ __launch_bounds__(64, 1)
void scan_kernel(float* __restrict__ O)
{
    __shared__ __align__(16) float buf[3][16 * 256];   // 3 x 16KB

    const int b = blockIdx.x;
    const int n = threadIdx.x;
    float* obase = O + (size_t)b * Tn * Dn;

    float* br = buf[0];   // holds chunk c   (read target)
    float* b1 = buf[1];   // holds chunk c+1
    float* b2 = buf[2];   // holds chunk c+2 (issue target after rotate)

    f32x4 sv[8];
    float st = 0.f;

    // ---- prologue: fill the pipe (chunks 0,1,2), compute chunk 0
    issue_chunk(br, RP(0));                    // L0
    issue_chunk(b1, RP(1));                    // L1
    issue_chunk(b2, RP(2));                    // L2
    WAITV(32);                                 // drain L0, keep L1,L2
    compute_chunk(br, n, st, sv);              // c0 -> sv = S_0
    { float* t = br; br = b1; b1 = b2; b2 = t; }

    // ---- c = 1 (peeled: no stores in queue yet -> N=32)
    issue_chunk(b2, RP(3));                    // L3
    WAITV(32);                                 // drain L1, keep L2,L3
    store_s(SP(0), sv);                        // S_0
    compute_chunk(br, n, st, sv);              // c1 -> S_1
    { float* t = br; br = b1; b1 = b2; b2 = t; }

    // ---- steady state: c = 2..125
    #pragma unroll 1
    for (int c = 2; c <= 125; ++c) {
        issue_chunk(b2, RP(c + 2));            // L_{c+2}
        WAITV(40);                             // drain L_c (+older), keep L_{c+1},S_{c-2},L_{c+2}
        store_s(SP(c - 1), sv);                // S_{c-1}
        compute_chunk(br, n, st, sv);          // c -> S_c
        { float* t = br; br = b1; b1 = b2; b2 = t; }
    }

    // ---- c = 126: no issue. queue [L126,S123,L127,S124]
    WAITV(24);                                 // drain L126, keep S124,L127
    store_s(SP(125), sv);
    compute_chunk(br, n, st, sv);              // c126 -> S_126
    { float* t = br; br = b1; b1 = b2; b2 = t; }

    // ---- c = 127: queue [L127,S124,S125]
    WAITV(16);                                 // drain L127
    store_s(SP(126), sv);
    compute_chunk(br, n, st, sv);              // c127 -> S_127
    store_s(SP(127), sv);
}

#undef RP
#undef SP

// ---------------------------------------------------------------------------
// Kernel 3: output projection, in-place. grid (BT/64), block 256. (unchanged)
// ---------------------------------------------------------------------------
__global__ __launch_bounds__(256)
void out_kernel(const float* __restrict__ out_w, const float* __restrict__ out_b,
                float* __restrict__ O)
{
    __shared__ float Ss[64][Nn + 4];   // Ss[t_local][n]
    __shared__ float wT[Nn][64 + 4];

    const int tid = threadIdx.x;
    const int r0  = blockIdx.x * 64;
    const int c   = tid & 15;
    const int g   = tid >> 4;

    // stage S: element (t = r0+tl, n) lives at O[(r0+n)*Dn + 128 + tl]
    for (int idx = tid; idx < 64 * 16; idx += 256) {
        int nn = idx >> 4, tg = idx & 15;
        float4 v = *(const float4*)&O[(size_t)(r0 + nn) * Dn + 128 + 4 * tg];
        Ss[4 * tg + 0][nn] = v.x;
        Ss[4 * tg + 1][nn] = v.y;
        Ss[4 * tg + 2][nn] = v.z;
        Ss[4 * tg + 3][nn] = v.w;
    }
    __syncthreads();

    for (int cb = 0; cb < Dn / 64; ++cb) {
        const int d0 = cb * 64;
        for (int idx = tid; idx < Nn * 64 / 4; idx += 256) {
            int dl = idx >> 4, n4 = (idx & 15) * 4;
            float4 wv = *(const float4*)&out_w[(size_t)(d0 + dl) * Nn + n4];
            wT[n4 + 0][dl] = wv.x;
            wT[n4 + 1][dl] = wv.y;
            wT[n4 + 2][dl] = wv.z;
            wT[n4 + 3][dl] = wv.w;
        }
        __syncthreads();

        float acc[4][4] = {};
        #pragma unroll
        for (int kq = 0; kq < Nn; kq += 4) {
            float4 wv0 = *(const float4*)&wT[kq + 0][4 * c];
            float4 wv1 = *(const float4*)&wT[kq + 1][4 * c];
            float4 wv2 = *(const float4*)&wT[kq + 2][4 * c];
            float4 wv3 = *(const float4*)&wT[kq + 3][4 * c];
            #pragma unroll
            for (int i = 0; i < 4; ++i) {
                int row = g + 16 * i;
                float4 xv = *(const float4*)&Ss[row][kq];
                acc[i][0] = fmaf(xv.x, wv0.x, fmaf(xv.y, wv1.x, fmaf(xv.z, wv2.x, fmaf(xv.w, wv3.x, acc[i][0]))));
                acc[i][1] = fmaf(xv.x, wv0.y, fmaf(xv.y, wv1.y, fmaf(xv.z, wv2.y, fmaf(xv.w, wv3.y, acc[i][1]))));
                acc[i][2] = fmaf(xv.x, wv0.z, fmaf(xv.y, wv1.z, fmaf(xv.z, wv2.z, fmaf(xv.w, wv3.z, acc[i][2]))));
                acc[i][3] = fmaf(xv.x, wv0.w, fmaf(xv.y, wv1.w, fmaf(xv.z, wv2.w, fmaf(xv.w, wv3.w, acc[i][3]))));
            }
        }

        float4 bb = *(const float4*)&out_b[d0 + 4 * c];
        #pragma unroll
        for (int i = 0; i < 4; ++i) {
            int row = g + 16 * i;
            float4 o = make_float4(acc[i][0] + bb.x, acc[i][1] + bb.y,
                                   acc[i][2] + bb.z, acc[i][3] + bb.w);
            *(float4*)&O[(size_t)(r0 + row) * Dn + d0 + 4 * c] = o;
        }
        __syncthreads();
    }
}

extern "C" void kernel_launch(void* const* d_in, const int* in_sizes, int n_in,
                              void* d_out, int out_size, void* d_ws, size_t ws_size,
                              hipStream_t stream)
{
    const float* x      = (const float*)d_in[0];
    const float* conv_w = (const float*)d_in[1];
    const float* in_w   = (const float*)d_in[2];
    const float* in_b   = (const float*)d_in[3];
    const float* dt_w   = (const float*)d_in[4];
    const float* dt_b   = (const float*)d_in[5];
    const float* tr_w   = (const float*)d_in[6];
    const float* out_w  = (const float*)d_in[7];
    const float* out_b  = (const float*)d_in[8];
    float* O = (float*)d_out;
    (void)d_ws; (void)ws_size;

    dim3 g1(Tn / TT2, Bn);
    prep_kernel<<<g1, 128, 0, stream>>>(x, conv_w, in_w, in_b, dt_w, dt_b, tr_w, O);

    scan_kernel<<<dim3(Bn), 64, 0, stream>>>(O);

    out_kernel<<<dim3((Bn * Tn) / 64), 256, 0, stream>>>(out_w, out_b, O);
}